// Round 11
// baseline (398.769 us; speedup 1.0000x reference)
//
#include <hip/hip_runtime.h>
#include <cmath>

#define NN 4096
#define KK 32
#define DD 256
#define HH 128
#define G3 384   // 3*H
#define CH 16    // xw0 chunk steps staged in LDS
#define RH 136   // padded f16 stride of one h-half in the h1 ring

typedef __attribute__((ext_vector_type(8))) _Float16 h8;
typedef __attribute__((ext_vector_type(4))) float f32x4;

// ---------------------------------------------------------------------------
// Kernel 1 (proven R8): fused setup. Block 0: order/pos/len + prefix + scale.
// Blocks 1..18: pack {W_hh0, W_ih1, W_hh1} into f16 B-fragments.
// Pack layout: [mat(3)][nt(24)][kt(4)][lane(64)][j(8)];
// B[k][n]: n = nt*16 + (lane&15), k = kt*32 + (lane>>4)*8 + j.
// ---------------------------------------------------------------------------
__global__ __launch_bounds__(1024) void setup_k(
    const int* __restrict__ labels, const float* __restrict__ lin_v,
    const float* __restrict__ lin_g,
    const float* __restrict__ Whh0, const float* __restrict__ Wih1,
    const float* __restrict__ Whh1,
    int* __restrict__ order, int* __restrict__ pos, int* __restrict__ len,
    int* __restrict__ starts, float* __restrict__ scale,
    _Float16* __restrict__ P) {
  if (blockIdx.x != 0) {
    const int gid = (int)(blockIdx.x - 1) * 1024 + threadIdx.x;  // 18432
    if (gid >= 18432) return;
    const int lane = gid & 63;
    const int kt = (gid >> 6) & 3;
    const int nt = (gid >> 8) % 24;
    const int mat = (gid >> 8) / 24;
    const float* W = (mat == 0) ? Whh0 : (mat == 1 ? Wih1 : Whh1);
    const int n = nt * 16 + (lane & 15);
    const int kbase = kt * 32 + (lane >> 4) * 8;
    _Float16* dst = P + (size_t)gid * 8;
#pragma unroll
    for (int j = 0; j < 8; ++j) dst[j] = (_Float16)W[(size_t)n * HH + kbase + j];
    return;
  }
  const int t = threadIdx.x;
  const int wv = t >> 6, lane = t & 63;
  __shared__ int lens_s[KK];
  for (int cc = 0; cc < 2; ++cc) {
    const int c = wv * 2 + cc;
    int count = 0;
    for (int base = 0; base < NN; base += 64) {
      const int i = base + lane;
      const bool f = (labels[i] == c);
      const unsigned long long m = __ballot(f);
      if (f) {
        const int p = count + __popcll(m & ((1ull << lane) - 1ull));
        order[c * NN + p] = i;
        pos[i] = p;
      }
      count += __popcll(m);
    }
    if (lane == 0) { lens_s[c] = count; len[c] = count; }
  }
  __syncthreads();
  if (wv == 0) {
    int lm = 0;
    if (lane < KK) { const int l = lens_s[lane]; lm = (l > 0) ? l : 1; }
    int inc = lm;
    for (int off = 1; off < KK; off <<= 1) {
      const int o = __shfl_up(inc, off);
      if (lane >= off) inc += o;
    }
    if (lane < KK) starts[lane] = inc - lm;
    if (lane == KK - 1) starts[KK] = inc;
  } else if (wv == 1) {
    float s = 0.f;
    for (int j = lane; j < G3; j += 64) { const float v = lin_v[j]; s += v * v; }
    for (int off = 32; off; off >>= 1) s += __shfl_down(s, off);
    if (lane == 0) scale[0] = lin_g[0] / sqrtf(s);
  }
}

// ---------------------------------------------------------------------------
// Kernel 2 (proven): out[slot(i)][g] = bias[g] + sum_d X[i][d]*W[g][d]
// ---------------------------------------------------------------------------
__global__ __launch_bounds__(256) void gemm_ih_k(
    const float* __restrict__ X, const float* __restrict__ W,
    const float* __restrict__ bias,
    const int* __restrict__ labels, const int* __restrict__ pos,
    const int* __restrict__ starts, float* __restrict__ out) {
  __shared__ float Xs[16][132];
  __shared__ float Ws[16][68];
  const int i0 = blockIdx.x * 128;
  const int g0 = blockIdx.y * 64;
  const int t  = threadIdx.x;
  const int it = t & 15;
  const int gt = t >> 4;
  float acc[8][4] = {};
  for (int k0 = 0; k0 < DD; k0 += 16) {
#pragma unroll
    for (int l = 0; l < 2; ++l) {
      const int u = t * 2 + l;
      const int r = u >> 2;
      const int cq = u & 3;
      const float4 f = *(const float4*)(X + (size_t)(i0 + r) * DD + k0 + cq * 4);
      Xs[cq * 4 + 0][r] = f.x; Xs[cq * 4 + 1][r] = f.y;
      Xs[cq * 4 + 2][r] = f.z; Xs[cq * 4 + 3][r] = f.w;
    }
    {
      const int r = t >> 2;
      const int cq = t & 3;
      const float4 f = *(const float4*)(W + (size_t)(g0 + r) * DD + k0 + cq * 4);
      Ws[cq * 4 + 0][r] = f.x; Ws[cq * 4 + 1][r] = f.y;
      Ws[cq * 4 + 2][r] = f.z; Ws[cq * 4 + 3][r] = f.w;
    }
    __syncthreads();
#pragma unroll
    for (int k = 0; k < 16; ++k) {
      float a[8], b[4];
#pragma unroll
      for (int x = 0; x < 8; ++x) a[x] = Xs[k][it * 8 + x];
#pragma unroll
      for (int y = 0; y < 4; ++y) b[y] = Ws[k][gt * 4 + y];
#pragma unroll
      for (int x = 0; x < 8; ++x)
#pragma unroll
        for (int y = 0; y < 4; ++y)
          acc[x][y] += a[x] * b[y];
    }
    __syncthreads();
  }
  const float4 bs = *(const float4*)(bias + g0 + gt * 4);
#pragma unroll
  for (int x = 0; x < 8; ++x) {
    const int gi = i0 + it * 8 + x;
    const int slot = starts[labels[gi]] + pos[gi];
    float4 o;
    o.x = acc[x][0] + bs.x; o.y = acc[x][1] + bs.y;
    o.z = acc[x][2] + bs.z; o.w = acc[x][3] + bs.w;
    *(float4*)(out + (size_t)slot * G3 + g0 + gt * 4) = o;
  }
}

// ---------------------------------------------------------------------------
// Kernel 3: FUSED 2-layer GRU (R10 structure) + DUAL-LANE gates.
// A rows 0,4 = h_hi and rows 1,5 = h_lo -> D rows {0,1} (lanes 0-15) and
// {4,5} (lanes 16-31) hold identical matvec sums, so lanes 0..31 each
// compute ONE gate (t = 32v + (lane&31)): lanes<16 use accs {0,2,4},
// lanes 16-31 use accs {1,3,5}. Gate serial chain halved; bit-identical.
//   waves 0-3 (G0): per-step hw0 -> L0 gate -> h1 ring (hi/lo).
//   waves 4-7 (G1): every 8 steps, batched xw1 16-row GEMM from the ring.
//   waves 8-11(G2): per-step hw1 (+xw1 chunk, +b_ih1) -> h2, lag 9.
// One barrier/iter. Tail: scoring for this cluster.
// ---------------------------------------------------------------------------
__global__ __launch_bounds__(768) void gru_fused_k(
    const float* __restrict__ xw0,          // sorted [Mtot+2CH][384] fp32
    const _Float16* __restrict__ pack,      // [3][24][4][64][8] f16 frags
    const float* __restrict__ b_hh0, const float* __restrict__ b_ih0,
    const float* __restrict__ b_ih1, const float* __restrict__ b_hh1,
    const int* __restrict__ starts, const int* __restrict__ len,
    const int* __restrict__ order, const float* __restrict__ sent,
    const float* __restrict__ lin_v, const float* __restrict__ scale,
    const float* __restrict__ lin_b, float* __restrict__ out) {
  const int c = blockIdx.x;
  const int t = threadIdx.x;
  const int wv = t >> 6, lane = t & 63;
  const int group = wv >> 2;                // 0:L0-hw  1:xw1-batch  2:L1-hw
  const int v = wv & 3;
  // ---- preload B fragments (96 VGPRs, loop-invariant) ---------------------
  h8 B[6][4];
  {
    const _Float16* mp = pack + (size_t)group * (24 * 4 * 64 * 8);
#pragma unroll
    for (int i = 0; i < 6; ++i) {
      const int nt = (i >> 1) * 8 + 2 * v + (i & 1);
#pragma unroll
      for (int kt = 0; kt < 4; ++kt)
        B[i][kt] = *(const h8*)(mp + ((size_t)(nt * 4 + kt) * 64 + lane) * 8);
    }
  }
  const int L = len[c], start = starts[c];
  const int Lr = (L > 0) ? L : 1;
  const bool use_bih0 = (L == 0);
  // ---- LDS ----------------------------------------------------------------
  __shared__ __align__(16) float xwbuf[2 * CH * G3];     // 48 KB dbuf chunks
  __shared__ __align__(16) _Float16 ring[16][2 * RH];    // h1 ring, padded
  __shared__ __align__(16) _Float16 hp2[2][2][HH];       // h2 [par][hi/lo]
  __shared__ float xw1buf[2][8][G3];                     // [chunk&1][step][gate]
  __shared__ float ce_s[HH];
  __shared__ float vbuf[G3];
  __shared__ float sc_s[2048];
  __shared__ float sc_red;
  {
    _Float16* rp = &ring[0][0];
    for (int u = t; u < 16 * 2 * RH; u += 768) rp[u] = (_Float16)0.f;
  }
  if (t < HH) {
    hp2[0][0][t] = (_Float16)0.f; hp2[0][1][t] = (_Float16)0.f;
    hp2[1][0][t] = (_Float16)0.f; hp2[1][1][t] = (_Float16)0.f;
  }
  // prologue: stage xw0 chunk 0 into buffer 0
  if (!use_bih0) {
    const float4* src = (const float4*)(xw0 + (size_t)start * G3);
    float4* dst = (float4*)xwbuf;
    dst[t] = src[t];
    dst[t + 768] = src[t + 768];
  }
  // ---- per-lane gate constants (lanes 0..31: one gate each) ---------------
  const int tg = 32 * v + (lane & 31);      // this lane's gate id
  float bhr = 0.f, bhz = 0.f, bhn = 0.f;    // W_hh bias for gate tg
  float bir = 0.f, biz = 0.f, bin = 0.f;    // input bias / fallback
  float h = 0.f;                            // h1 slice (G0) / h2 slice (G2)
  if (lane < 32) {
    if (group == 0) {
      bhr = b_hh0[tg]; bhz = b_hh0[HH + tg]; bhn = b_hh0[2 * HH + tg];
      if (use_bih0) {
        bir = b_ih0[tg]; biz = b_ih0[HH + tg]; bin = b_ih0[2 * HH + tg];
      }
    } else if (group == 2) {
      bhr = b_hh1[tg]; bhz = b_hh1[HH + tg]; bhn = b_hh1[2 * HH + tg];
      bir = b_ih1[tg]; biz = b_ih1[HH + tg]; bin = b_ih1[2 * HH + tg];
    }
  }
  __syncthreads();   // init + chunk-0 staging visible
  const int q = lane >> 4;
  const int row = lane & 15;
  const int hs = (row == 0 || row == 4) ? 0 : 1;  // rows 0,4 = hi; 1,5 = lo
  const int ab = (lane >> 4) & 1;                  // acc base: 0 or 1
  for (int it2 = 0; it2 < Lr + 9; ++it2) {
    const int par = it2 & 1;
    // ---- prefetch next xw0 chunk (all threads) ---------------------------
    if (!use_bih0 && (it2 & (CH - 1)) == 0 && it2 + CH < Lr) {
      const float4* src = (const float4*)(xw0 + (size_t)(start + it2 + CH) * G3);
      float4* dst = (float4*)(xwbuf + ((((it2 >> 4) + 1) & 1) ? CH * G3 : 0));
      dst[t] = src[t];
      dst[t + 768] = src[t + 768];
    }
    if (group == 0) {
      if (it2 < Lr) {
        // hoist gate inputs (LDS latency hides under MFMAs)
        float xr = bir, xz = biz, xn = bin;
        if (!use_bih0 && lane < 32) {
          const float* xrow = xwbuf + ((it2 >> 4) & 1) * (CH * G3)
                                    + (it2 & (CH - 1)) * G3;
          xr = xrow[tg]; xz = xrow[HH + tg]; xn = xrow[2 * HH + tg];
        }
        const _Float16* abse = &ring[(it2 - 1) & 15][hs * RH];
        h8 A[4];
#pragma unroll
        for (int kt = 0; kt < 4; ++kt)
          A[kt] = *(const h8*)(abse + kt * 32 + q * 8);
        f32x4 a0[6];
#pragma unroll
        for (int i = 0; i < 6; ++i) {
          f32x4 a = {0.f, 0.f, 0.f, 0.f};
#pragma unroll
          for (int kt = 0; kt < 4; ++kt)
            a = __builtin_amdgcn_mfma_f32_16x16x32_f16(A[kt], B[i][kt], a, 0, 0, 0);
          a0[i] = a;
        }
        if (lane < 32) {                     // ONE gate per lane
          const float hwr = a0[ab][0] + a0[ab][1];
          const float hwz = a0[ab + 2][0] + a0[ab + 2][1];
          const float hwn = a0[ab + 4][0] + a0[ab + 4][1];
          const float r = 1.f / (1.f + __expf(-(xr + bhr + hwr)));
          const float z = 1.f / (1.f + __expf(-(xz + bhz + hwz)));
          float tgt = xn + r * (bhn + hwn);
          tgt = fminf(fmaxf(tgt, -15.f), 15.f);
          const float e = __expf(2.f * tgt);
          const float n = (e - 1.f) / (e + 1.f);
          h = (1.f - z) * n + z * h;
          const _Float16 hi = (_Float16)h;
          _Float16* rs = &ring[it2 & 15][0];
          rs[tg] = hi;  rs[RH + tg] = (_Float16)(h - (float)hi);
        }
      }
    } else if (group == 1) {
      if (it2 >= 8 && (it2 & 7) == 0 && it2 - 8 < Lr) {
        // batched xw1 for chunk steps [it2-8, it2): A rows = 8 steps x hi/lo
        const int c8 = it2 - 8;
        const int m = lane & 15;
        const int s = m >> 1, half = m & 1;
        const _Float16* abse = &ring[(c8 + s) & 15][half * RH];
        h8 A[4];
#pragma unroll
        for (int kt = 0; kt < 4; ++kt)
          A[kt] = *(const h8*)(abse + kt * 32 + q * 8);
        const int cbuf = (c8 >> 3) & 1;
        float* xo0 = &xw1buf[cbuf][2 * q][0];       // step 2q  (rows 4q,4q+1)
        float* xo1 = &xw1buf[cbuf][2 * q + 1][0];   // step 2q+1(rows 4q+2,4q+3)
#pragma unroll
        for (int i = 0; i < 6; ++i) {
          f32x4 a = {0.f, 0.f, 0.f, 0.f};
#pragma unroll
          for (int kt = 0; kt < 4; ++kt)
            a = __builtin_amdgcn_mfma_f32_16x16x32_f16(A[kt], B[i][kt], a, 0, 0, 0);
          const int nt = (i >> 1) * 8 + 2 * v + (i & 1);
          const int col = nt * 16 + (lane & 15);
          xo0[col] = a[0] + a[1];
          xo1[col] = a[2] + a[3];
        }
      }
    } else {
      if (it2 >= 9) {                        // L1: j = it2 - 9
        const int j = it2 - 9;
        float xr = 0.f, xz = 0.f, xn = 0.f;
        if (lane < 32) {
          const float* xi = xw1buf[(j >> 3) & 1][j & 7];
          xr = xi[tg] + bir; xz = xi[HH + tg] + biz; xn = xi[2 * HH + tg] + bin;
        }
        const _Float16* hbase = hp2[par][hs];
        h8 A[4];
#pragma unroll
        for (int kt = 0; kt < 4; ++kt)
          A[kt] = *(const h8*)(hbase + kt * 32 + q * 8);
        f32x4 a1[6];
#pragma unroll
        for (int i = 0; i < 6; ++i) {
          f32x4 a = {0.f, 0.f, 0.f, 0.f};
#pragma unroll
          for (int kt = 0; kt < 4; ++kt)
            a = __builtin_amdgcn_mfma_f32_16x16x32_f16(A[kt], B[i][kt], a, 0, 0, 0);
          a1[i] = a;
        }
        if (lane < 32) {
          const float hwr = a1[ab][0] + a1[ab][1];
          const float hwz = a1[ab + 2][0] + a1[ab + 2][1];
          const float hwn = a1[ab + 4][0] + a1[ab + 4][1];
          const float r = 1.f / (1.f + __expf(-(xr + bhr + hwr)));
          const float z = 1.f / (1.f + __expf(-(xz + bhz + hwz)));
          float tgt = xn + r * (bhn + hwn);
          tgt = fminf(fmaxf(tgt, -15.f), 15.f);
          const float e = __expf(2.f * tgt);
          const float n = (e - 1.f) / (e + 1.f);
          h = (1.f - z) * n + z * h;
          const _Float16 hi = (_Float16)h;
          hp2[par ^ 1][0][tg] = hi;
          hp2[par ^ 1][1][tg] = (_Float16)(h - (float)hi);
        }
      }
    }
    __syncthreads();   // the ONLY barrier per iter
  }
  // ---- scoring tail (cluster c's sentences) -------------------------------
  if (L == 0) return;
  if (group == 2 && lane < 32) ce_s[tg] = h;
  if (t < G3) vbuf[t] = lin_v[t];
  __syncthreads();
  if (wv == 0) {   // ce . v[256:384] (per-cluster constant)
    float cd = ce_s[lane] * vbuf[DD + lane] + ce_s[64 + lane] * vbuf[DD + 64 + lane];
    for (int off = 32; off; off >>= 1) cd += __shfl_down(cd, off);
    if (lane == 0) sc_red = cd;
  }
  __syncthreads();
  const float cedot = sc_red;
  const float sc = scale[0], lb = lin_b[0];
  const int Lc = (L < 2048) ? L : 2048;
  for (int p = wv; p < Lc; p += 12) {
    const int i = order[c * NN + p];
    const float4 a = *(const float4*)(sent + (size_t)i * DD + lane * 4);
    const float4 b = ((const float4*)vbuf)[lane];
    float d = a.x * b.x + a.y * b.y + a.z * b.z + a.w * b.w;
    for (int off = 32; off; off >>= 1) d += __shfl_down(d, off);
    if (lane == 0) sc_s[p] = tanhf(sc * (d + cedot) + lb);
  }
  __syncthreads();
  if (wv == 0) {   // cluster sum -> 1/sum
    float s = 0.f;
    for (int p = lane; p < Lc; p += 64) s += sc_s[p];
    for (int off = 32; off; off >>= 1) s += __shfl_down(s, off);
    if (lane == 0) sc_red = 1.f / s;
  }
  __syncthreads();
  const float inv = sc_red;
  for (int p = t; p < Lc; p += 768) {
    const int i = order[c * NN + p];
    float ps = __expf(-(float)(i + 1) * 0.0625f);   // 1/4096^(1/3) == 1/16
    ps = fmaxf(0.5f, ps);
    out[i] = 0.5f * (sc_s[p] * inv) + 0.5f * ps;
  }
}

// ---------------------------------------------------------------------------
extern "C" void kernel_launch(void* const* d_in, const int* in_sizes, int n_in,
                              void* d_out, int out_size, void* d_ws, size_t ws_size,
                              hipStream_t stream) {
  const float* sent   = (const float*)d_in[0];
  const int*   labels = (const int*)d_in[1];
  const float* W_ih0  = (const float*)d_in[2];
  const float* W_hh0  = (const float*)d_in[3];
  const float* b_ih0  = (const float*)d_in[4];
  const float* b_hh0  = (const float*)d_in[5];
  const float* W_ih1  = (const float*)d_in[6];
  const float* W_hh1  = (const float*)d_in[7];
  const float* b_ih1  = (const float*)d_in[8];
  const float* b_hh1  = (const float*)d_in[9];
  const float* lin_v  = (const float*)d_in[10];
  const float* lin_g  = (const float*)d_in[11];
  const float* lin_b  = (const float*)d_in[12];
  float* out = (float*)d_out;

  char* ws = (char*)d_ws;
  size_t off = 0;
  auto alloc = [&](size_t bytes) -> void* {
    void* p = ws + off;
    off = (off + bytes + 255) & ~(size_t)255;
    return p;
  };
  int*   order  = (int*)  alloc((size_t)KK * NN * sizeof(int));
  int*   pos    = (int*)  alloc(NN * sizeof(int));
  int*   len    = (int*)  alloc(KK * sizeof(int));
  int*   starts = (int*)  alloc((KK + 1) * sizeof(int));
  float* scale  = (float*)alloc(sizeof(float));
  _Float16* pack = (_Float16*)alloc((size_t)18432 * 8 * sizeof(_Float16));
  float* xw     = (float*)alloc((size_t)(NN + KK + 2 * CH) * G3 * sizeof(float));
  (void)ws_size; (void)in_sizes; (void)n_in; (void)out_size;

  setup_k<<<dim3(19), dim3(1024), 0, stream>>>(
      labels, lin_v, lin_g, W_hh0, W_ih1, W_hh1,
      order, pos, len, starts, scale, pack);
  gemm_ih_k<<<dim3(32, 6), dim3(256), 0, stream>>>(
      sent, W_ih0, b_ih0, labels, pos, starts, xw);
  gru_fused_k<<<dim3(KK), dim3(768), 0, stream>>>(
      xw, pack, b_hh0, b_ih0, b_ih1, b_hh1, starts, len,
      order, sent, lin_v, scale, lin_b, out);
}

// Round 12
// 277.858 us; speedup vs baseline: 1.4352x; 1.4352x over previous
//
#include <hip/hip_runtime.h>
#include <cmath>

#define NN 4096
#define KK 32
#define DD 256
#define HH 128
#define G3 384   // 3*H
#define CH 16    // xw0 chunk steps staged in LDS
#define RH 136   // padded f16 stride of one h-half in the h1 ring

typedef __attribute__((ext_vector_type(8))) _Float16 h8;
typedef __attribute__((ext_vector_type(4))) float f32x4;

// ---------------------------------------------------------------------------
// Kernel 1 (proven R8): fused setup. Block 0: order/pos/len + prefix + scale.
// Blocks 1..18: pack {W_hh0, W_ih1, W_hh1} into f16 B-fragments.
// Pack layout: [mat(3)][nt(24)][kt(4)][lane(64)][j(8)];
// B[k][n]: n = nt*16 + (lane&15), k = kt*32 + (lane>>4)*8 + j.
// ---------------------------------------------------------------------------
__global__ __launch_bounds__(1024) void setup_k(
    const int* __restrict__ labels, const float* __restrict__ lin_v,
    const float* __restrict__ lin_g,
    const float* __restrict__ Whh0, const float* __restrict__ Wih1,
    const float* __restrict__ Whh1,
    int* __restrict__ order, int* __restrict__ pos, int* __restrict__ len,
    int* __restrict__ starts, float* __restrict__ scale,
    _Float16* __restrict__ P) {
  if (blockIdx.x != 0) {
    const int gid = (int)(blockIdx.x - 1) * 1024 + threadIdx.x;  // 18432
    if (gid >= 18432) return;
    const int lane = gid & 63;
    const int kt = (gid >> 6) & 3;
    const int nt = (gid >> 8) % 24;
    const int mat = (gid >> 8) / 24;
    const float* W = (mat == 0) ? Whh0 : (mat == 1 ? Wih1 : Whh1);
    const int n = nt * 16 + (lane & 15);
    const int kbase = kt * 32 + (lane >> 4) * 8;
    _Float16* dst = P + (size_t)gid * 8;
#pragma unroll
    for (int j = 0; j < 8; ++j) dst[j] = (_Float16)W[(size_t)n * HH + kbase + j];
    return;
  }
  const int t = threadIdx.x;
  const int wv = t >> 6, lane = t & 63;
  __shared__ int lens_s[KK];
  for (int cc = 0; cc < 2; ++cc) {
    const int c = wv * 2 + cc;
    int count = 0;
    for (int base = 0; base < NN; base += 64) {
      const int i = base + lane;
      const bool f = (labels[i] == c);
      const unsigned long long m = __ballot(f);
      if (f) {
        const int p = count + __popcll(m & ((1ull << lane) - 1ull));
        order[c * NN + p] = i;
        pos[i] = p;
      }
      count += __popcll(m);
    }
    if (lane == 0) { lens_s[c] = count; len[c] = count; }
  }
  __syncthreads();
  if (wv == 0) {
    int lm = 0;
    if (lane < KK) { const int l = lens_s[lane]; lm = (l > 0) ? l : 1; }
    int inc = lm;
    for (int off = 1; off < KK; off <<= 1) {
      const int o = __shfl_up(inc, off);
      if (lane >= off) inc += o;
    }
    if (lane < KK) starts[lane] = inc - lm;
    if (lane == KK - 1) starts[KK] = inc;
  } else if (wv == 1) {
    float s = 0.f;
    for (int j = lane; j < G3; j += 64) { const float v = lin_v[j]; s += v * v; }
    for (int off = 32; off; off >>= 1) s += __shfl_down(s, off);
    if (lane == 0) scale[0] = lin_g[0] / sqrtf(s);
  }
}

// ---------------------------------------------------------------------------
// Kernel 2 (proven): out[slot(i)][g] = bias[g] + sum_d X[i][d]*W[g][d]
// ---------------------------------------------------------------------------
__global__ __launch_bounds__(256) void gemm_ih_k(
    const float* __restrict__ X, const float* __restrict__ W,
    const float* __restrict__ bias,
    const int* __restrict__ labels, const int* __restrict__ pos,
    const int* __restrict__ starts, float* __restrict__ out) {
  __shared__ float Xs[16][132];
  __shared__ float Ws[16][68];
  const int i0 = blockIdx.x * 128;
  const int g0 = blockIdx.y * 64;
  const int t  = threadIdx.x;
  const int it = t & 15;
  const int gt = t >> 4;
  float acc[8][4] = {};
  for (int k0 = 0; k0 < DD; k0 += 16) {
#pragma unroll
    for (int l = 0; l < 2; ++l) {
      const int u = t * 2 + l;
      const int r = u >> 2;
      const int cq = u & 3;
      const float4 f = *(const float4*)(X + (size_t)(i0 + r) * DD + k0 + cq * 4);
      Xs[cq * 4 + 0][r] = f.x; Xs[cq * 4 + 1][r] = f.y;
      Xs[cq * 4 + 2][r] = f.z; Xs[cq * 4 + 3][r] = f.w;
    }
    {
      const int r = t >> 2;
      const int cq = t & 3;
      const float4 f = *(const float4*)(W + (size_t)(g0 + r) * DD + k0 + cq * 4);
      Ws[cq * 4 + 0][r] = f.x; Ws[cq * 4 + 1][r] = f.y;
      Ws[cq * 4 + 2][r] = f.z; Ws[cq * 4 + 3][r] = f.w;
    }
    __syncthreads();
#pragma unroll
    for (int k = 0; k < 16; ++k) {
      float a[8], b[4];
#pragma unroll
      for (int x = 0; x < 8; ++x) a[x] = Xs[k][it * 8 + x];
#pragma unroll
      for (int y = 0; y < 4; ++y) b[y] = Ws[k][gt * 4 + y];
#pragma unroll
      for (int x = 0; x < 8; ++x)
#pragma unroll
        for (int y = 0; y < 4; ++y)
          acc[x][y] += a[x] * b[y];
    }
    __syncthreads();
  }
  const float4 bs = *(const float4*)(bias + g0 + gt * 4);
#pragma unroll
  for (int x = 0; x < 8; ++x) {
    const int gi = i0 + it * 8 + x;
    const int slot = starts[labels[gi]] + pos[gi];
    float4 o;
    o.x = acc[x][0] + bs.x; o.y = acc[x][1] + bs.y;
    o.z = acc[x][2] + bs.z; o.w = acc[x][3] + bs.w;
    *(float4*)(out + (size_t)slot * G3 + g0 + gt * 4) = o;
  }
}

// ---------------------------------------------------------------------------
// Kernel 3: FUSED 2-layer GRU + DUAL-LANE gates (R11 fixed: NO dynamic
// register-array indexing — accumulator picks use uniform reads + cndmask).
// A rows 0,4 = h_hi; rows 1,5 = h_lo -> lanes 0-15 (regs of rows 0,1) and
// lanes 16-31 (rows 4,5) hold identical matvec sums; lanes 0..31 each
// compute ONE gate (tg = 32v + (lane&31)).
//   waves 0-3 (G0): per-step hw0 -> L0 gate -> h1 ring (hi/lo).
//   waves 4-7 (G1): every 8 steps, batched xw1 16-row GEMM from the ring.
//   waves 8-11(G2): per-step hw1 (+xw1 chunk, +b_ih1) -> h2, lag 9.
// One barrier/iter. Tail: scoring for this cluster.
// ---------------------------------------------------------------------------
__global__ __launch_bounds__(768) void gru_fused_k(
    const float* __restrict__ xw0,          // sorted [Mtot+2CH][384] fp32
    const _Float16* __restrict__ pack,      // [3][24][4][64][8] f16 frags
    const float* __restrict__ b_hh0, const float* __restrict__ b_ih0,
    const float* __restrict__ b_ih1, const float* __restrict__ b_hh1,
    const int* __restrict__ starts, const int* __restrict__ len,
    const int* __restrict__ order, const float* __restrict__ sent,
    const float* __restrict__ lin_v, const float* __restrict__ scale,
    const float* __restrict__ lin_b, float* __restrict__ out) {
  const int c = blockIdx.x;
  const int t = threadIdx.x;
  const int wv = t >> 6, lane = t & 63;
  const int group = wv >> 2;                // 0:L0-hw  1:xw1-batch  2:L1-hw
  const int v = wv & 3;
  // ---- preload B fragments (96 VGPRs, loop-invariant) ---------------------
  h8 B[6][4];
  {
    const _Float16* mp = pack + (size_t)group * (24 * 4 * 64 * 8);
#pragma unroll
    for (int i = 0; i < 6; ++i) {
      const int nt = (i >> 1) * 8 + 2 * v + (i & 1);
#pragma unroll
      for (int kt = 0; kt < 4; ++kt)
        B[i][kt] = *(const h8*)(mp + ((size_t)(nt * 4 + kt) * 64 + lane) * 8);
    }
  }
  const int L = len[c], start = starts[c];
  const int Lr = (L > 0) ? L : 1;
  const bool use_bih0 = (L == 0);
  // ---- LDS ----------------------------------------------------------------
  __shared__ __align__(16) float xwbuf[2 * CH * G3];     // 48 KB dbuf chunks
  __shared__ __align__(16) _Float16 ring[16][2 * RH];    // h1 ring, padded
  __shared__ __align__(16) _Float16 hp2[2][2][HH];       // h2 [par][hi/lo]
  __shared__ float xw1buf[2][8][G3];                     // [chunk&1][step][gate]
  __shared__ float ce_s[HH];
  __shared__ float vbuf[G3];
  __shared__ float sc_s[2048];
  __shared__ float sc_red;
  {
    _Float16* rp = &ring[0][0];
    for (int u = t; u < 16 * 2 * RH; u += 768) rp[u] = (_Float16)0.f;
  }
  if (t < HH) {
    hp2[0][0][t] = (_Float16)0.f; hp2[0][1][t] = (_Float16)0.f;
    hp2[1][0][t] = (_Float16)0.f; hp2[1][1][t] = (_Float16)0.f;
  }
  // prologue: stage xw0 chunk 0 into buffer 0
  if (!use_bih0) {
    const float4* src = (const float4*)(xw0 + (size_t)start * G3);
    float4* dst = (float4*)xwbuf;
    dst[t] = src[t];
    dst[t + 768] = src[t + 768];
  }
  // ---- per-lane gate constants (lanes 0..31: one gate each) ---------------
  const int tg = 32 * v + (lane & 31);      // this lane's gate id
  float bhr = 0.f, bhz = 0.f, bhn = 0.f;    // W_hh bias for gate tg
  float bir = 0.f, biz = 0.f, bin = 0.f;    // input bias / fallback
  float h = 0.f;                            // h1 slice (G0) / h2 slice (G2)
  if (lane < 32) {
    if (group == 0) {
      bhr = b_hh0[tg]; bhz = b_hh0[HH + tg]; bhn = b_hh0[2 * HH + tg];
      if (use_bih0) {
        bir = b_ih0[tg]; biz = b_ih0[HH + tg]; bin = b_ih0[2 * HH + tg];
      }
    } else if (group == 2) {
      bhr = b_hh1[tg]; bhz = b_hh1[HH + tg]; bhn = b_hh1[2 * HH + tg];
      bir = b_ih1[tg]; biz = b_ih1[HH + tg]; bin = b_ih1[2 * HH + tg];
    }
  }
  __syncthreads();   // init + chunk-0 staging visible
  const int q = lane >> 4;
  const int row = lane & 15;
  const int hs = (row == 0 || row == 4) ? 0 : 1;  // rows 0,4 = hi; 1,5 = lo
  const bool hiacc = ((lane >> 4) & 1) != 0;      // lanes 16-31: use odd accs
  for (int it2 = 0; it2 < Lr + 9; ++it2) {
    const int par = it2 & 1;
    // ---- prefetch next xw0 chunk (all threads) ---------------------------
    if (!use_bih0 && (it2 & (CH - 1)) == 0 && it2 + CH < Lr) {
      const float4* src = (const float4*)(xw0 + (size_t)(start + it2 + CH) * G3);
      float4* dst = (float4*)(xwbuf + ((((it2 >> 4) + 1) & 1) ? CH * G3 : 0));
      dst[t] = src[t];
      dst[t + 768] = src[t + 768];
    }
    if (group == 0) {
      if (it2 < Lr) {
        // hoist gate inputs (LDS latency hides under MFMAs)
        float xr = bir, xz = biz, xn = bin;
        if (!use_bih0 && lane < 32) {
          const float* xrow = xwbuf + ((it2 >> 4) & 1) * (CH * G3)
                                    + (it2 & (CH - 1)) * G3;
          xr = xrow[tg]; xz = xrow[HH + tg]; xn = xrow[2 * HH + tg];
        }
        const _Float16* abse = &ring[(it2 - 1) & 15][hs * RH];
        h8 A[4];
#pragma unroll
        for (int kt = 0; kt < 4; ++kt)
          A[kt] = *(const h8*)(abse + kt * 32 + q * 8);
        f32x4 a0[6];
#pragma unroll
        for (int i = 0; i < 6; ++i) {
          f32x4 a = {0.f, 0.f, 0.f, 0.f};
#pragma unroll
          for (int kt = 0; kt < 4; ++kt)
            a = __builtin_amdgcn_mfma_f32_16x16x32_f16(A[kt], B[i][kt], a, 0, 0, 0);
          a0[i] = a;
        }
        if (lane < 32) {                     // ONE gate per lane (cndmask pick)
          const float hwrA = a0[0][0] + a0[0][1], hwrB = a0[1][0] + a0[1][1];
          const float hwzA = a0[2][0] + a0[2][1], hwzB = a0[3][0] + a0[3][1];
          const float hwnA = a0[4][0] + a0[4][1], hwnB = a0[5][0] + a0[5][1];
          const float hwr = hiacc ? hwrB : hwrA;
          const float hwz = hiacc ? hwzB : hwzA;
          const float hwn = hiacc ? hwnB : hwnA;
          const float r = 1.f / (1.f + __expf(-(xr + bhr + hwr)));
          const float z = 1.f / (1.f + __expf(-(xz + bhz + hwz)));
          float tgt = xn + r * (bhn + hwn);
          tgt = fminf(fmaxf(tgt, -15.f), 15.f);
          const float e = __expf(2.f * tgt);
          const float n = (e - 1.f) / (e + 1.f);
          h = (1.f - z) * n + z * h;
          const _Float16 hi = (_Float16)h;
          _Float16* rs = &ring[it2 & 15][0];
          rs[tg] = hi;  rs[RH + tg] = (_Float16)(h - (float)hi);
        }
      }
    } else if (group == 1) {
      if (it2 >= 8 && (it2 & 7) == 0 && it2 - 8 < Lr) {
        // batched xw1 for chunk steps [it2-8, it2): A rows = 8 steps x hi/lo
        const int c8 = it2 - 8;
        const int m = lane & 15;
        const int s = m >> 1, half = m & 1;
        const _Float16* abse = &ring[(c8 + s) & 15][half * RH];
        h8 A[4];
#pragma unroll
        for (int kt = 0; kt < 4; ++kt)
          A[kt] = *(const h8*)(abse + kt * 32 + q * 8);
        const int cbuf = (c8 >> 3) & 1;
        float* xo0 = &xw1buf[cbuf][2 * q][0];       // step 2q  (rows 4q,4q+1)
        float* xo1 = &xw1buf[cbuf][2 * q + 1][0];   // step 2q+1(rows 4q+2,4q+3)
#pragma unroll
        for (int i = 0; i < 6; ++i) {
          f32x4 a = {0.f, 0.f, 0.f, 0.f};
#pragma unroll
          for (int kt = 0; kt < 4; ++kt)
            a = __builtin_amdgcn_mfma_f32_16x16x32_f16(A[kt], B[i][kt], a, 0, 0, 0);
          const int nt = (i >> 1) * 8 + 2 * v + (i & 1);
          const int col = nt * 16 + (lane & 15);
          xo0[col] = a[0] + a[1];
          xo1[col] = a[2] + a[3];
        }
      }
    } else {
      if (it2 >= 9) {                        // L1: j = it2 - 9
        const int j = it2 - 9;
        float xr = 0.f, xz = 0.f, xn = 0.f;
        if (lane < 32) {
          const float* xi = xw1buf[(j >> 3) & 1][j & 7];
          xr = xi[tg] + bir; xz = xi[HH + tg] + biz; xn = xi[2 * HH + tg] + bin;
        }
        const _Float16* hbase = hp2[par][hs];
        h8 A[4];
#pragma unroll
        for (int kt = 0; kt < 4; ++kt)
          A[kt] = *(const h8*)(hbase + kt * 32 + q * 8);
        f32x4 a1[6];
#pragma unroll
        for (int i = 0; i < 6; ++i) {
          f32x4 a = {0.f, 0.f, 0.f, 0.f};
#pragma unroll
          for (int kt = 0; kt < 4; ++kt)
            a = __builtin_amdgcn_mfma_f32_16x16x32_f16(A[kt], B[i][kt], a, 0, 0, 0);
          a1[i] = a;
        }
        if (lane < 32) {
          const float hwrA = a1[0][0] + a1[0][1], hwrB = a1[1][0] + a1[1][1];
          const float hwzA = a1[2][0] + a1[2][1], hwzB = a1[3][0] + a1[3][1];
          const float hwnA = a1[4][0] + a1[4][1], hwnB = a1[5][0] + a1[5][1];
          const float hwr = hiacc ? hwrB : hwrA;
          const float hwz = hiacc ? hwzB : hwzA;
          const float hwn = hiacc ? hwnB : hwnA;
          const float r = 1.f / (1.f + __expf(-(xr + bhr + hwr)));
          const float z = 1.f / (1.f + __expf(-(xz + bhz + hwz)));
          float tgt = xn + r * (bhn + hwn);
          tgt = fminf(fmaxf(tgt, -15.f), 15.f);
          const float e = __expf(2.f * tgt);
          const float n = (e - 1.f) / (e + 1.f);
          h = (1.f - z) * n + z * h;
          const _Float16 hi = (_Float16)h;
          hp2[par ^ 1][0][tg] = hi;
          hp2[par ^ 1][1][tg] = (_Float16)(h - (float)hi);
        }
      }
    }
    __syncthreads();   // the ONLY barrier per iter
  }
  // ---- scoring tail (cluster c's sentences) -------------------------------
  if (L == 0) return;
  if (group == 2 && lane < 32) ce_s[tg] = h;
  if (t < G3) vbuf[t] = lin_v[t];
  __syncthreads();
  if (wv == 0) {   // ce . v[256:384] (per-cluster constant)
    float cd = ce_s[lane] * vbuf[DD + lane] + ce_s[64 + lane] * vbuf[DD + 64 + lane];
    for (int off = 32; off; off >>= 1) cd += __shfl_down(cd, off);
    if (lane == 0) sc_red = cd;
  }
  __syncthreads();
  const float cedot = sc_red;
  const float sc = scale[0], lb = lin_b[0];
  const int Lc = (L < 2048) ? L : 2048;
  for (int p = wv; p < Lc; p += 12) {
    const int i = order[c * NN + p];
    const float4 a = *(const float4*)(sent + (size_t)i * DD + lane * 4);
    const float4 b = ((const float4*)vbuf)[lane];
    float d = a.x * b.x + a.y * b.y + a.z * b.z + a.w * b.w;
    for (int off = 32; off; off >>= 1) d += __shfl_down(d, off);
    if (lane == 0) sc_s[p] = tanhf(sc * (d + cedot) + lb);
  }
  __syncthreads();
  if (wv == 0) {   // cluster sum -> 1/sum
    float s = 0.f;
    for (int p = lane; p < Lc; p += 64) s += sc_s[p];
    for (int off = 32; off; off >>= 1) s += __shfl_down(s, off);
    if (lane == 0) sc_red = 1.f / s;
  }
  __syncthreads();
  const float inv = sc_red;
  for (int p = t; p < Lc; p += 768) {
    const int i = order[c * NN + p];
    float ps = __expf(-(float)(i + 1) * 0.0625f);   // 1/4096^(1/3) == 1/16
    ps = fmaxf(0.5f, ps);
    out[i] = 0.5f * (sc_s[p] * inv) + 0.5f * ps;
  }
}

// ---------------------------------------------------------------------------
extern "C" void kernel_launch(void* const* d_in, const int* in_sizes, int n_in,
                              void* d_out, int out_size, void* d_ws, size_t ws_size,
                              hipStream_t stream) {
  const float* sent   = (const float*)d_in[0];
  const int*   labels = (const int*)d_in[1];
  const float* W_ih0  = (const float*)d_in[2];
  const float* W_hh0  = (const float*)d_in[3];
  const float* b_ih0  = (const float*)d_in[4];
  const float* b_hh0  = (const float*)d_in[5];
  const float* W_ih1  = (const float*)d_in[6];
  const float* W_hh1  = (const float*)d_in[7];
  const float* b_ih1  = (const float*)d_in[8];
  const float* b_hh1  = (const float*)d_in[9];
  const float* lin_v  = (const float*)d_in[10];
  const float* lin_g  = (const float*)d_in[11];
  const float* lin_b  = (const float*)d_in[12];
  float* out = (float*)d_out;

  char* ws = (char*)d_ws;
  size_t off = 0;
  auto alloc = [&](size_t bytes) -> void* {
    void* p = ws + off;
    off = (off + bytes + 255) & ~(size_t)255;
    return p;
  };
  int*   order  = (int*)  alloc((size_t)KK * NN * sizeof(int));
  int*   pos    = (int*)  alloc(NN * sizeof(int));
  int*   len    = (int*)  alloc(KK * sizeof(int));
  int*   starts = (int*)  alloc((KK + 1) * sizeof(int));
  float* scale  = (float*)alloc(sizeof(float));
  _Float16* pack = (_Float16*)alloc((size_t)18432 * 8 * sizeof(_Float16));
  float* xw     = (float*)alloc((size_t)(NN + KK + 2 * CH) * G3 * sizeof(float));
  (void)ws_size; (void)in_sizes; (void)n_in; (void)out_size;

  setup_k<<<dim3(19), dim3(1024), 0, stream>>>(
      labels, lin_v, lin_g, W_hh0, W_ih1, W_hh1,
      order, pos, len, starts, scale, pack);
  gemm_ih_k<<<dim3(32, 6), dim3(256), 0, stream>>>(
      sent, W_ih0, b_ih0, labels, pos, starts, xw);
  gru_fused_k<<<dim3(KK), dim3(768), 0, stream>>>(
      xw, pack, b_hh0, b_ih0, b_ih1, b_hh1, starts, len,
      order, sent, lin_v, scale, lin_b, out);
}

// Round 13
// 240.739 us; speedup vs baseline: 1.6564x; 1.1542x over previous
//
#include <hip/hip_runtime.h>
#include <cmath>

#define NN 4096
#define KK 32
#define DD 256
#define HH 128
#define G3 384   // 3*H
#define CH 16    // xw0 chunk steps staged in LDS
#define RH 136   // padded f16 stride of one h-half in the h1 ring

typedef __attribute__((ext_vector_type(8))) _Float16 h8;
typedef __attribute__((ext_vector_type(4))) float f32x4;

// ---------------------------------------------------------------------------
// Kernel 1: PREP — all pre-recurrence work in one launch, 273 blocks x 256.
//   blocks 0..71  : pack {W_hh0, W_ih1, W_hh1} into f16 B-fragments
//                   layout [mat(3)][nt(24)][kt(4)][lane(64)][j(8)]
//   blocks 72..79 : per-cluster order lists + len (1 cluster per wave)
//   block  80     : weight-norm scale g/||v||
//   blocks 81..272: xw0 gemm, UNSORTED (slot = sentence index) -> no
//                   dependency on the order blocks (rec gathers via order)
// ---------------------------------------------------------------------------
__global__ __launch_bounds__(256) void prep_k(
    const int* __restrict__ labels, const float* __restrict__ lin_v,
    const float* __restrict__ lin_g,
    const float* __restrict__ Whh0, const float* __restrict__ Wih1,
    const float* __restrict__ Whh1,
    const float* __restrict__ sent, const float* __restrict__ W_ih0,
    const float* __restrict__ b_ih0,
    int* __restrict__ order, int* __restrict__ len, float* __restrict__ scale,
    _Float16* __restrict__ P, float* __restrict__ xw) {
  const int blk = blockIdx.x;
  const int t = threadIdx.x;
  if (blk < 72) {                       // ---- pack ----
    const int gid = blk * 256 + t;      // < 18432
    const int lane = gid & 63;
    const int kt = (gid >> 6) & 3;
    const int nt = (gid >> 8) % 24;
    const int mat = (gid >> 8) / 24;
    const float* W = (mat == 0) ? Whh0 : (mat == 1 ? Wih1 : Whh1);
    const int n = nt * 16 + (lane & 15);
    const int kbase = kt * 32 + (lane >> 4) * 8;
    _Float16* dst = P + (size_t)gid * 8;
#pragma unroll
    for (int j = 0; j < 8; ++j) dst[j] = (_Float16)W[(size_t)n * HH + kbase + j];
    return;
  }
  if (blk < 80) {                       // ---- order/len: 1 cluster/wave ----
    const int wv = t >> 6, lane = t & 63;
    const int c = (blk - 72) * 4 + wv;
    int count = 0;
    for (int base = 0; base < NN; base += 64) {
      const int i = base + lane;
      const bool f = (labels[i] == c);
      const unsigned long long m = __ballot(f);
      if (f) order[c * NN + count + __popcll(m & ((1ull << lane) - 1ull))] = i;
      count += __popcll(m);
    }
    if (lane == 0) len[c] = count;
    return;
  }
  if (blk == 80) {                      // ---- scale ----
    if (t < 64) {
      float s = 0.f;
      for (int j = t; j < G3; j += 64) { const float v = lin_v[j]; s += v * v; }
      for (int off = 32; off; off >>= 1) s += __shfl_down(s, off);
      if (t == 0) scale[0] = lin_g[0] / sqrtf(s);
    }
    return;
  }
  // ---- gemm: xw[i][g] = b_ih0[g] + sum_d sent[i][d] * W_ih0[g][d] ----
  __shared__ float Xs[16][132];
  __shared__ float Ws[16][68];
  const int g = blk - 81;               // 0..191
  const int i0 = (g & 31) * 128;
  const int g0 = (g >> 5) * 64;
  const int it = t & 15;
  const int gt = t >> 4;
  float acc[8][4] = {};
  for (int k0 = 0; k0 < DD; k0 += 16) {
#pragma unroll
    for (int l = 0; l < 2; ++l) {
      const int u = t * 2 + l;
      const int r = u >> 2;
      const int cq = u & 3;
      const float4 f = *(const float4*)(sent + (size_t)(i0 + r) * DD + k0 + cq * 4);
      Xs[cq * 4 + 0][r] = f.x; Xs[cq * 4 + 1][r] = f.y;
      Xs[cq * 4 + 2][r] = f.z; Xs[cq * 4 + 3][r] = f.w;
    }
    {
      const int r = t >> 2;
      const int cq = t & 3;
      const float4 f = *(const float4*)(W_ih0 + (size_t)(g0 + r) * DD + k0 + cq * 4);
      Ws[cq * 4 + 0][r] = f.x; Ws[cq * 4 + 1][r] = f.y;
      Ws[cq * 4 + 2][r] = f.z; Ws[cq * 4 + 3][r] = f.w;
    }
    __syncthreads();
#pragma unroll
    for (int k = 0; k < 16; ++k) {
      float a[8], b[4];
#pragma unroll
      for (int x = 0; x < 8; ++x) a[x] = Xs[k][it * 8 + x];
#pragma unroll
      for (int y = 0; y < 4; ++y) b[y] = Ws[k][gt * 4 + y];
#pragma unroll
      for (int x = 0; x < 8; ++x)
#pragma unroll
        for (int y = 0; y < 4; ++y)
          acc[x][y] += a[x] * b[y];
    }
    __syncthreads();
  }
  const float4 bs = *(const float4*)(b_ih0 + g0 + gt * 4);
#pragma unroll
  for (int x = 0; x < 8; ++x) {
    const int gi = i0 + it * 8 + x;
    float4 o;
    o.x = acc[x][0] + bs.x; o.y = acc[x][1] + bs.y;
    o.z = acc[x][2] + bs.z; o.w = acc[x][3] + bs.w;
    *(float4*)(xw + (size_t)gi * G3 + g0 + gt * 4) = o;
  }
}

// ---------------------------------------------------------------------------
// Kernel 2: FUSED 2-layer GRU + DUAL-LANE gates (R12 structure, proven).
// xw0 is UNSORTED; chunk staging gathers rows via order[] (clamped).
//   waves 0-3 (G0): per-step hw0 -> L0 gate -> h1 ring (hi/lo).
//   waves 4-7 (G1): every 8 steps, batched xw1 16-row GEMM from the ring.
//   waves 8-11(G2): per-step hw1 (+xw1 chunk, +b_ih1) -> h2, lag 9.
// Lanes 0..31 each compute ONE gate via uniform acc reads + cndmask picks
// (A rows 0,4 = h_hi; 1,5 = h_lo). One barrier/iter. Tail: scoring.
// ---------------------------------------------------------------------------
__global__ __launch_bounds__(768) void gru_fused_k(
    const float* __restrict__ xw0,          // UNSORTED [NN][384] fp32
    const _Float16* __restrict__ pack,      // [3][24][4][64][8] f16 frags
    const float* __restrict__ b_hh0, const float* __restrict__ b_ih0,
    const float* __restrict__ b_ih1, const float* __restrict__ b_hh1,
    const int* __restrict__ len, const int* __restrict__ order,
    const float* __restrict__ sent,
    const float* __restrict__ lin_v, const float* __restrict__ scale,
    const float* __restrict__ lin_b, float* __restrict__ out) {
  const int c = blockIdx.x;
  const int t = threadIdx.x;
  const int wv = t >> 6, lane = t & 63;
  const int group = wv >> 2;                // 0:L0-hw  1:xw1-batch  2:L1-hw
  const int v = wv & 3;
  // ---- preload B fragments (96 VGPRs, loop-invariant) ---------------------
  h8 B[6][4];
  {
    const _Float16* mp = pack + (size_t)group * (24 * 4 * 64 * 8);
#pragma unroll
    for (int i = 0; i < 6; ++i) {
      const int nt = (i >> 1) * 8 + 2 * v + (i & 1);
#pragma unroll
      for (int kt = 0; kt < 4; ++kt)
        B[i][kt] = *(const h8*)(mp + ((size_t)(nt * 4 + kt) * 64 + lane) * 8);
    }
  }
  const int L = len[c];
  const int Lr = (L > 0) ? L : 1;
  const bool use_bih0 = (L == 0);
  // gather-staging constants: element e -> chunk row u = e/96, float4 f = e%96
  const int u0 = t / 96, f0 = t - u0 * 96;
  const int u1 = (t + 768) / 96, f1 = (t + 768) - u1 * 96;
  // ---- LDS ----------------------------------------------------------------
  __shared__ __align__(16) float xwbuf[2 * CH * G3];     // 48 KB dbuf chunks
  __shared__ __align__(16) _Float16 ring[16][2 * RH];    // h1 ring, padded
  __shared__ __align__(16) _Float16 hp2[2][2][HH];       // h2 [par][hi/lo]
  __shared__ float xw1buf[2][8][G3];                     // [chunk&1][step][gate]
  __shared__ float ce_s[HH];
  __shared__ float vbuf[G3];
  __shared__ float sc_s[2048];
  __shared__ float sc_red;
  {
    _Float16* rp = &ring[0][0];
    for (int u = t; u < 16 * 2 * RH; u += 768) rp[u] = (_Float16)0.f;
  }
  if (t < HH) {
    hp2[0][0][t] = (_Float16)0.f; hp2[0][1][t] = (_Float16)0.f;
    hp2[1][0][t] = (_Float16)0.f; hp2[1][1][t] = (_Float16)0.f;
  }
  // prologue: stage chunk 0 (gathered via order, clamped)
  if (!use_bih0) {
    const float4* src = (const float4*)xw0;
    float4* dst = (float4*)xwbuf;
    const int r0 = (u0 < L) ? order[c * NN + u0] : 0;
    const int r1 = (u1 < L) ? order[c * NN + u1] : 0;
    dst[t] = src[(size_t)r0 * 96 + f0];
    dst[t + 768] = src[(size_t)r1 * 96 + f1];
  }
  // ---- per-lane gate constants (lanes 0..31: one gate each) ---------------
  const int tg = 32 * v + (lane & 31);      // this lane's gate id
  float bhr = 0.f, bhz = 0.f, bhn = 0.f;    // W_hh bias for gate tg
  float bir = 0.f, biz = 0.f, bin = 0.f;    // input bias / fallback
  float h = 0.f;                            // h1 slice (G0) / h2 slice (G2)
  if (lane < 32) {
    if (group == 0) {
      bhr = b_hh0[tg]; bhz = b_hh0[HH + tg]; bhn = b_hh0[2 * HH + tg];
      if (use_bih0) {
        bir = b_ih0[tg]; biz = b_ih0[HH + tg]; bin = b_ih0[2 * HH + tg];
      }
    } else if (group == 2) {
      bhr = b_hh1[tg]; bhz = b_hh1[HH + tg]; bhn = b_hh1[2 * HH + tg];
      bir = b_ih1[tg]; biz = b_ih1[HH + tg]; bin = b_ih1[2 * HH + tg];
    }
  }
  __syncthreads();   // init + chunk-0 staging visible
  const int q = lane >> 4;
  const int row = lane & 15;
  const int hs = (row == 0 || row == 4) ? 0 : 1;  // rows 0,4 = hi; 1,5 = lo
  const bool hiacc = ((lane >> 4) & 1) != 0;      // lanes 16-31: use odd accs
  for (int it2 = 0; it2 < Lr + 9; ++it2) {
    const int par = it2 & 1;
    // ---- prefetch next xw0 chunk (gathered, all threads) -----------------
    if (!use_bih0 && (it2 & (CH - 1)) == 0 && it2 + CH < Lr) {
      const float4* src = (const float4*)xw0;
      float4* dst = (float4*)(xwbuf + ((((it2 >> 4) + 1) & 1) ? CH * G3 : 0));
      const int p0 = it2 + CH + u0;
      const int p1 = it2 + CH + u1;
      const int r0 = (p0 < L) ? order[c * NN + p0] : 0;
      const int r1 = (p1 < L) ? order[c * NN + p1] : 0;
      dst[t] = src[(size_t)r0 * 96 + f0];
      dst[t + 768] = src[(size_t)r1 * 96 + f1];
    }
    if (group == 0) {
      if (it2 < Lr) {
        // hoist gate inputs (LDS latency hides under MFMAs)
        float xr = bir, xz = biz, xn = bin;
        if (!use_bih0 && lane < 32) {
          const float* xrow = xwbuf + ((it2 >> 4) & 1) * (CH * G3)
                                    + (it2 & (CH - 1)) * G3;
          xr = xrow[tg]; xz = xrow[HH + tg]; xn = xrow[2 * HH + tg];
        }
        const _Float16* abse = &ring[(it2 - 1) & 15][hs * RH];
        h8 A[4];
#pragma unroll
        for (int kt = 0; kt < 4; ++kt)
          A[kt] = *(const h8*)(abse + kt * 32 + q * 8);
        f32x4 a0[6];
#pragma unroll
        for (int i = 0; i < 6; ++i) {
          f32x4 a = {0.f, 0.f, 0.f, 0.f};
#pragma unroll
          for (int kt = 0; kt < 4; ++kt)
            a = __builtin_amdgcn_mfma_f32_16x16x32_f16(A[kt], B[i][kt], a, 0, 0, 0);
          a0[i] = a;
        }
        if (lane < 32) {                     // ONE gate per lane (cndmask pick)
          const float hwrA = a0[0][0] + a0[0][1], hwrB = a0[1][0] + a0[1][1];
          const float hwzA = a0[2][0] + a0[2][1], hwzB = a0[3][0] + a0[3][1];
          const float hwnA = a0[4][0] + a0[4][1], hwnB = a0[5][0] + a0[5][1];
          const float hwr = hiacc ? hwrB : hwrA;
          const float hwz = hiacc ? hwzB : hwzA;
          const float hwn = hiacc ? hwnB : hwnA;
          const float r = 1.f / (1.f + __expf(-(xr + bhr + hwr)));
          const float z = 1.f / (1.f + __expf(-(xz + bhz + hwz)));
          float tgt = xn + r * (bhn + hwn);
          tgt = fminf(fmaxf(tgt, -15.f), 15.f);
          const float e = __expf(2.f * tgt);
          const float n = (e - 1.f) / (e + 1.f);
          h = (1.f - z) * n + z * h;
          const _Float16 hi = (_Float16)h;
          _Float16* rs = &ring[it2 & 15][0];
          rs[tg] = hi;  rs[RH + tg] = (_Float16)(h - (float)hi);
        }
      }
    } else if (group == 1) {
      if (it2 >= 8 && (it2 & 7) == 0 && it2 - 8 < Lr) {
        // batched xw1 for chunk steps [it2-8, it2): A rows = 8 steps x hi/lo
        const int c8 = it2 - 8;
        const int m = lane & 15;
        const int s = m >> 1, half = m & 1;
        const _Float16* abse = &ring[(c8 + s) & 15][half * RH];
        h8 A[4];
#pragma unroll
        for (int kt = 0; kt < 4; ++kt)
          A[kt] = *(const h8*)(abse + kt * 32 + q * 8);
        const int cbuf = (c8 >> 3) & 1;
        float* xo0 = &xw1buf[cbuf][2 * q][0];       // step 2q  (rows 4q,4q+1)
        float* xo1 = &xw1buf[cbuf][2 * q + 1][0];   // step 2q+1(rows 4q+2,4q+3)
#pragma unroll
        for (int i = 0; i < 6; ++i) {
          f32x4 a = {0.f, 0.f, 0.f, 0.f};
#pragma unroll
          for (int kt = 0; kt < 4; ++kt)
            a = __builtin_amdgcn_mfma_f32_16x16x32_f16(A[kt], B[i][kt], a, 0, 0, 0);
          const int nt = (i >> 1) * 8 + 2 * v + (i & 1);
          const int col = nt * 16 + (lane & 15);
          xo0[col] = a[0] + a[1];
          xo1[col] = a[2] + a[3];
        }
      }
    } else {
      if (it2 >= 9) {                        // L1: j = it2 - 9
        const int j = it2 - 9;
        float xr = 0.f, xz = 0.f, xn = 0.f;
        if (lane < 32) {
          const float* xi = xw1buf[(j >> 3) & 1][j & 7];
          xr = xi[tg] + bir; xz = xi[HH + tg] + biz; xn = xi[2 * HH + tg] + bin;
        }
        const _Float16* hbase = hp2[par][hs];
        h8 A[4];
#pragma unroll
        for (int kt = 0; kt < 4; ++kt)
          A[kt] = *(const h8*)(hbase + kt * 32 + q * 8);
        f32x4 a1[6];
#pragma unroll
        for (int i = 0; i < 6; ++i) {
          f32x4 a = {0.f, 0.f, 0.f, 0.f};
#pragma unroll
          for (int kt = 0; kt < 4; ++kt)
            a = __builtin_amdgcn_mfma_f32_16x16x32_f16(A[kt], B[i][kt], a, 0, 0, 0);
          a1[i] = a;
        }
        if (lane < 32) {
          const float hwrA = a1[0][0] + a1[0][1], hwrB = a1[1][0] + a1[1][1];
          const float hwzA = a1[2][0] + a1[2][1], hwzB = a1[3][0] + a1[3][1];
          const float hwnA = a1[4][0] + a1[4][1], hwnB = a1[5][0] + a1[5][1];
          const float hwr = hiacc ? hwrB : hwrA;
          const float hwz = hiacc ? hwzB : hwzA;
          const float hwn = hiacc ? hwnB : hwnA;
          const float r = 1.f / (1.f + __expf(-(xr + bhr + hwr)));
          const float z = 1.f / (1.f + __expf(-(xz + bhz + hwz)));
          float tgt = xn + r * (bhn + hwn);
          tgt = fminf(fmaxf(tgt, -15.f), 15.f);
          const float e = __expf(2.f * tgt);
          const float n = (e - 1.f) / (e + 1.f);
          h = (1.f - z) * n + z * h;
          const _Float16 hi = (_Float16)h;
          hp2[par ^ 1][0][tg] = hi;
          hp2[par ^ 1][1][tg] = (_Float16)(h - (float)hi);
        }
      }
    }
    __syncthreads();   // the ONLY barrier per iter
  }
  // ---- scoring tail (cluster c's sentences) -------------------------------
  if (L == 0) return;
  if (group == 2 && lane < 32) ce_s[tg] = h;
  if (t < G3) vbuf[t] = lin_v[t];
  __syncthreads();
  if (wv == 0) {   // ce . v[256:384] (per-cluster constant)
    float cd = ce_s[lane] * vbuf[DD + lane] + ce_s[64 + lane] * vbuf[DD + 64 + lane];
    for (int off = 32; off; off >>= 1) cd += __shfl_down(cd, off);
    if (lane == 0) sc_red = cd;
  }
  __syncthreads();
  const float cedot = sc_red;
  const float sc = scale[0], lb = lin_b[0];
  const int Lc = (L < 2048) ? L : 2048;
  for (int p = wv; p < Lc; p += 12) {
    const int i = order[c * NN + p];
    const float4 a = *(const float4*)(sent + (size_t)i * DD + lane * 4);
    const float4 b = ((const float4*)vbuf)[lane];
    float d = a.x * b.x + a.y * b.y + a.z * b.z + a.w * b.w;
    for (int off = 32; off; off >>= 1) d += __shfl_down(d, off);
    if (lane == 0) sc_s[p] = tanhf(sc * (d + cedot) + lb);
  }
  __syncthreads();
  if (wv == 0) {   // cluster sum -> 1/sum
    float s = 0.f;
    for (int p = lane; p < Lc; p += 64) s += sc_s[p];
    for (int off = 32; off; off >>= 1) s += __shfl_down(s, off);
    if (lane == 0) sc_red = 1.f / s;
  }
  __syncthreads();
  const float inv = sc_red;
  for (int p = t; p < Lc; p += 768) {
    const int i = order[c * NN + p];
    float ps = __expf(-(float)(i + 1) * 0.0625f);   // 1/4096^(1/3) == 1/16
    ps = fmaxf(0.5f, ps);
    out[i] = 0.5f * (sc_s[p] * inv) + 0.5f * ps;
  }
}

// ---------------------------------------------------------------------------
extern "C" void kernel_launch(void* const* d_in, const int* in_sizes, int n_in,
                              void* d_out, int out_size, void* d_ws, size_t ws_size,
                              hipStream_t stream) {
  const float* sent   = (const float*)d_in[0];
  const int*   labels = (const int*)d_in[1];
  const float* W_ih0  = (const float*)d_in[2];
  const float* W_hh0  = (const float*)d_in[3];
  const float* b_ih0  = (const float*)d_in[4];
  const float* b_hh0  = (const float*)d_in[5];
  const float* W_ih1  = (const float*)d_in[6];
  const float* W_hh1  = (const float*)d_in[7];
  const float* b_ih1  = (const float*)d_in[8];
  const float* b_hh1  = (const float*)d_in[9];
  const float* lin_v  = (const float*)d_in[10];
  const float* lin_g  = (const float*)d_in[11];
  const float* lin_b  = (const float*)d_in[12];
  float* out = (float*)d_out;

  char* ws = (char*)d_ws;
  size_t off = 0;
  auto alloc = [&](size_t bytes) -> void* {
    void* p = ws + off;
    off = (off + bytes + 255) & ~(size_t)255;
    return p;
  };
  int*   order  = (int*)  alloc((size_t)KK * NN * sizeof(int));
  int*   len    = (int*)  alloc(KK * sizeof(int));
  float* scale  = (float*)alloc(sizeof(float));
  _Float16* pack = (_Float16*)alloc((size_t)18432 * 8 * sizeof(_Float16));
  float* xw     = (float*)alloc((size_t)NN * G3 * sizeof(float));
  (void)ws_size; (void)in_sizes; (void)n_in; (void)out_size;

  prep_k<<<dim3(273), dim3(256), 0, stream>>>(
      labels, lin_v, lin_g, W_hh0, W_ih1, W_hh1,
      sent, W_ih0, b_ih0, order, len, scale, pack, xw);
  gru_fused_k<<<dim3(KK), dim3(768), 0, stream>>>(
      xw, pack, b_hh0, b_ih0, b_ih1, b_hh1, len, order,
      sent, lin_v, scale, lin_b, out);
}